// Round 2
// baseline (128.354 us; speedup 1.0000x reference)
//
#include <hip/hip_runtime.h>
#include <math.h>
#include <stdint.h>

#define B_  16
#define NP_ 8192
#define NG_ 128
#define NC_ 80
#define PPB_ 64                // predictions per block (block = 256 thr, 4 quarters)
#define NBX_ (NP_ / PPB_)      // 128 blocks along preds per batch
#define NPROD_ (NBX_ * B_)     // 2048 producer blocks; block NPROD_ is the reducer
#define QCH_ (NC_ / 4)         // 20 logits per quarter in the CE phase

#define EPS_       1e-7f
#define IOU_THR_   0.5f
#define PEN_       0.1f
#define BOXW_      5.0f
#define SMALLSC_   2.0f
#define SMALLTH_   0.05f

// publication magics: a repeated single-dword poison fill can never match BOTH
#define MAG1_ 0xA5C3F00Du
#define MAG2_ 0x3E7B119Cu

// d_ws partials layout: part[blockIdx.x * 8 + i] for producer blocks.
// components: [n_match, n_valid, sum_loc, sum_ce] [sum_pen, sum_bce, MAG1, MAG2]
// Producer publishes with agent-scope release on word 6; reducer acquires it.
// Deadlock-free: only the reducer block waits; all producers are independent.

__global__ __launch_bounds__(256) void yolo_fused(
    const float* __restrict__ y_hat,   // (B, NP, 4) xywh
    const float* __restrict__ ygt,     // (B, NG, 4) xywh
    const float* __restrict__ obj,     // (B, NP)
    const float* __restrict__ clsp,    // (B, NP, NC)
    const int*   __restrict__ tgt,     // (B, NG)
    const int*   __restrict__ min_s,   // scalar (int)
    float*       part,                 // (NPROD_, 8) in d_ws
    float*       out)                  // scalar
{
    __shared__ float4 g4[NG_];                 // gt xyxy
    __shared__ float  garea[NG_], gws[NG_];
    __shared__ int    gtc[NG_];
    __shared__ float4 mbuf[4][PPB_];           // quarters publish {inter, uni, bi, 0}
    __shared__ float2 cpub[4][PPB_];           // per-quarter {local max, local expsum}
    __shared__ float  tlog[PPB_];              // target-class logit
    __shared__ float  bsum[16][6];             // reducer: per-batch sums

    // ---------------- reducer block: spin on magics, tree-reduce -------------
    if (blockIdx.x == NPROD_) {
        const int t   = threadIdx.x;           // 0..255
        const int b   = t >> 4;                // batch 0..15
        const int sub = t & 15;                // 16 lanes per batch
        float v[6] = {0.f, 0.f, 0.f, 0.f, 0.f, 0.f};
        for (int k = 0; k < NBX_ / 16; ++k) {  // 8 slots per lane
            const float* slot = part + ((size_t)b * NBX_ + sub + 16 * k) * 8;
            const uint32_t* us = (const uint32_t*)slot;
            for (;;) {
                uint32_t m1 = __hip_atomic_load(&us[6], __ATOMIC_ACQUIRE, __HIP_MEMORY_SCOPE_AGENT);
                uint32_t m2 = __hip_atomic_load(&us[7], __ATOMIC_RELAXED, __HIP_MEMORY_SCOPE_AGENT);
                if (m1 == MAG1_ && m2 == MAG2_) break;
                __builtin_amdgcn_s_sleep(1);
            }
            float4 a = *(const float4*)slot;   // ordered after the acquire above
            v[0] += a.x; v[1] += a.y; v[2] += a.z; v[3] += a.w;
            v[4] += slot[4]; v[5] += slot[5];
        }
        #pragma unroll
        for (int i = 0; i < 6; ++i) {          // reduce the 16-lane group
            v[i] += __shfl_xor(v[i], 1, 64);
            v[i] += __shfl_xor(v[i], 2, 64);
            v[i] += __shfl_xor(v[i], 4, 64);
            v[i] += __shfl_xor(v[i], 8, 64);
        }
        if (sub == 0) {
            #pragma unroll
            for (int i = 0; i < 6; ++i) bsum[b][i] = v[i];
        }
        __syncthreads();
        if (t < 16) {
            float nm = bsum[t][0], nv = bsum[t][1];
            float loc = nm > 0.f ? bsum[t][2] / nm : 0.f;
            float ce  = nm > 0.f ? bsum[t][3] / nm : 0.f;
            float ob  = nv > 0.f ? bsum[t][5] / nv : 0.f;
            float per = BOXW_ * loc + ob + bsum[t][4] + ce;
            float pbv = 0.f, cnt = 0.f;
            if (nv > 0.f) { pbv = per; cnt = 1.f; }
            pbv += __shfl_xor(pbv, 1, 64); cnt += __shfl_xor(cnt, 1, 64);
            pbv += __shfl_xor(pbv, 2, 64); cnt += __shfl_xor(cnt, 2, 64);
            pbv += __shfl_xor(pbv, 4, 64); cnt += __shfl_xor(cnt, 4, 64);
            pbv += __shfl_xor(pbv, 8, 64); cnt += __shfl_xor(cnt, 8, 64);
            if (t == 0) out[0] = pbv / fmaxf(cnt, 1.f);
        }
        return;
    }

    // ---------------- producer blocks ----------------------------------------
    const int b   = blockIdx.x / NBX_;
    const int tid = threadIdx.x;
    const int pl  = tid & 63;                  // local pred id (lane)
    const int q   = tid >> 6;                  // quarter: IoU j in [32q, 32q+32)
    const int p   = (blockIdx.x % NBX_) * PPB_ + pl;

    // stage GT boxes: xywh -> xyxy(float4), area, small-obj weight, class
    if (tid < NG_) {
        float4 gb = *(const float4*)(ygt + ((size_t)b * NG_ + tid) * 4);
        float x1 = gb.x - gb.z * 0.5f, y1 = gb.y - gb.w * 0.5f;
        float x2 = gb.x + gb.z * 0.5f, y2 = gb.y + gb.w * 0.5f;
        g4[tid] = make_float4(x1, y1, x2, y2);
        garea[tid] = (x2 - x1) * (y2 - y1);
        gws[tid]   = ((gb.z < SMALLTH_) || (gb.w < SMALLTH_)) ? SMALLSC_ : 1.0f;
        gtc[tid]   = tgt[b * NG_ + tid];
    }
    __syncthreads();

    const float min_score = (float)min_s[0];

    // pred box -> xyxy (all 4 quarters of a pred load the same box; L1-served)
    float4 pb = *(const float4*)(y_hat + ((size_t)b * NP_ + p) * 4);
    float px1 = pb.x - pb.z * 0.5f, py1 = pb.y - pb.w * 0.5f;
    float px2 = pb.x + pb.z * 0.5f, py2 = pb.y + pb.w * 0.5f;
    float area_p = (px2 - px1) * (py2 - py1);

    // quarter-range argmax IoU, division-free (unions > 0).
    // strict '>' + ascending j == first-index (jnp.argmax) semantics.
    float bi_inter = -1.0f, bi_union = 1.0f;
    const int j0 = q * 32;
    int bi = j0;
    #pragma unroll 8
    for (int jj = 0; jj < 32; ++jj) {
        int j = j0 + jj;
        float4 g = g4[j];                       // wave-uniform addr -> LDS broadcast
        float w = fmaxf(fminf(px2, g.z) - fmaxf(px1, g.x), 0.0f);
        float h = fmaxf(fminf(py2, g.w) - fmaxf(py1, g.y), 0.0f);
        float inter = w * h;
        float uni = area_p + garea[j] - inter;  // reference iou_mat has no eps
        bool better = inter * bi_union > bi_inter * uni;
        bi_inter = better ? inter : bi_inter;
        bi_union = better ? uni   : bi_union;
        bi       = better ? j     : bi;
    }

    mbuf[q][pl] = make_float4(bi_inter, bi_union, (float)bi, 0.f);
    __syncthreads();

    // ALL quarters merge in ascending quarter order (identical result per pred;
    // strict > keeps lowest j on ties == jnp.argmax)
    {
        float4 m0 = mbuf[0][pl];
        bi_inter = m0.x; bi_union = m0.y; bi = (int)m0.z;
        #pragma unroll
        for (int k = 1; k < 4; ++k) {
            float4 o = mbuf[k][pl];
            if (o.x * bi_union > bi_inter * o.y) {
                bi_inter = o.x; bi_union = o.y; bi = (int)o.z;
            }
        }
    }
    float max_iou = bi_inter / bi_union;

    float s = obj[(size_t)b * NP_ + p];         // same addr in all quarters; cached
    bool valid   = s > min_score;
    bool matched = valid && (max_iou > IOU_THR_);

    // ---- CE softmax, 4-way parallel, ONE barrier: each quarter publishes its
    // local (max, sum exp(x - local_max)); quarter 0 rescales and combines. ----
    const float* rowq = clsp + ((size_t)b * NP_ + p) * NC_ + q * QCH_;
    if (matched) {
        float4 v0 = ((const float4*)rowq)[0];
        float4 v1 = ((const float4*)rowq)[1];
        float4 v2 = ((const float4*)rowq)[2];
        float4 v3 = ((const float4*)rowq)[3];
        float4 v4 = ((const float4*)rowq)[4];
        float m = fmaxf(
            fmaxf(fmaxf(fmaxf(v0.x, v0.y), fmaxf(v0.z, v0.w)),
                  fmaxf(fmaxf(v1.x, v1.y), fmaxf(v1.z, v1.w))),
            fmaxf(fmaxf(fmaxf(v2.x, v2.y), fmaxf(v2.z, v2.w)),
                  fmaxf(fmaxf(fmaxf(v3.x, v3.y), fmaxf(v3.z, v3.w)),
                        fmaxf(fmaxf(v4.x, v4.y), fmaxf(v4.z, v4.w)))));
        float se = 0.f;
        se += expf(v0.x - m) + expf(v0.y - m) + expf(v0.z - m) + expf(v0.w - m);
        se += expf(v1.x - m) + expf(v1.y - m) + expf(v1.z - m) + expf(v1.w - m);
        se += expf(v2.x - m) + expf(v2.y - m) + expf(v2.z - m) + expf(v2.w - m);
        se += expf(v3.x - m) + expf(v3.y - m) + expf(v3.z - m) + expf(v3.w - m);
        se += expf(v4.x - m) + expf(v4.y - m) + expf(v4.z - m) + expf(v4.w - m);
        cpub[q][pl] = make_float2(m, se);
        int tcl = gtc[bi];
        if (tcl / QCH_ == q)                    // owner quarter: line is L1-hot
            tlog[pl] = rowq[tcl - q * QCH_];
    }
    __syncthreads();

    if (q != 0) return;   // all waves already passed the last barrier

    float f_loc = 0.f, f_ce = 0.f, f_pen = 0.f, f_bce = 0.f;
    float n_m = matched ? 1.f : 0.f;
    float n_v = valid   ? 1.f : 0.f;
    if (valid && !matched) f_pen = PEN_ * s;

    if (valid) {
        float lbl = matched ? 1.f : 0.f;
        float bce = fmaxf(s, 0.f) - s * lbl + log1pf(expf(-fabsf(s)));
        float w_obj = (matched && s < 0.5f) ? 2.f : 1.f;
        f_bce = bce * w_obj;
    }

    if (matched) {
        float wsm = gws[bi];
        float4 g = g4[bi];
        float bx1 = g.x, by1 = g.y, bx2 = g.z, by2 = g.w;
        // CIoU(pred, gt[bi]) op-for-op with reference (with eps)
        float b1a = (px2 - px1) * (py2 - py1);
        float b2a = (bx2 - bx1) * (by2 - by1);
        float iw = fmaxf(fminf(px2, bx2) - fmaxf(px1, bx1), 0.f);
        float ih = fmaxf(fminf(py2, by2) - fmaxf(py1, by1), 0.f);
        float inter = iw * ih;
        float uni = b1a + b2a - inter + EPS_;
        float iou = inter / uni;
        float cw = fmaxf(px2, bx2) - fminf(px1, bx1);
        float ch = fmaxf(py2, by2) - fminf(py1, by1);
        float c2 = cw * cw + ch * ch + EPS_;
        float dx = (px1 + px2) * 0.5f - (bx1 + bx2) * 0.5f;
        float dy = (py1 + py2) * 0.5f - (by1 + by2) * 0.5f;
        float rho2 = dx * dx + dy * dy;
        float w1 = px2 - px1, h1 = py2 - py1;
        float w2 = bx2 - bx1, h2 = by2 - by1;
        float dat = atanf(w1 / (h1 + EPS_)) - atanf(w2 / (h2 + EPS_));
        float v = (float)(4.0 / (M_PI * M_PI)) * dat * dat;
        float alpha = v / (1.f - iou + v + EPS_);
        float ciou = iou - (rho2 / c2 + alpha * v);
        f_loc = (1.f - ciou) * wsm;

        // combine the 4 quarter softmax partials (rescale to global max)
        float2 c0 = cpub[0][pl], c1 = cpub[1][pl], c2q = cpub[2][pl], c3 = cpub[3][pl];
        float M = fmaxf(fmaxf(c0.x, c1.x), fmaxf(c2q.x, c3.x));
        float se = c0.y  * expf(c0.x  - M) + c1.y * expf(c1.x - M)
                 + c2q.y * expf(c2q.x - M) + c3.y * expf(c3.x - M);
        float ce = -(tlog[pl] - M - logf(se));
        f_ce = ce * wsm;
    }

    // wave 0 owns the reduce: shuffle-reduce and publish the block's slot
    float vals[6] = { n_m, n_v, f_loc, f_ce, f_pen, f_bce };
    #pragma unroll
    for (int i = 0; i < 6; ++i) {
        float v = vals[i];
        #pragma unroll
        for (int off = 32; off > 0; off >>= 1)
            v += __shfl_down(v, off, 64);
        vals[i] = v;
    }
    if (pl == 0) {
        float* slot = part + (size_t)blockIdx.x * 8;
        *(float4*)slot = make_float4(vals[0], vals[1], vals[2], vals[3]);
        slot[4] = vals[4];
        slot[5] = vals[5];
        uint32_t* us = (uint32_t*)slot;
        __hip_atomic_store(&us[7], MAG2_, __ATOMIC_RELAXED, __HIP_MEMORY_SCOPE_AGENT);
        __hip_atomic_store(&us[6], MAG1_, __ATOMIC_RELEASE, __HIP_MEMORY_SCOPE_AGENT);
    }
}

extern "C" void kernel_launch(void* const* d_in, const int* in_sizes, int n_in,
                              void* d_out, int out_size, void* d_ws, size_t ws_size,
                              hipStream_t stream) {
    const float* y_hat = (const float*)d_in[0];
    const float* ygt   = (const float*)d_in[1];
    const float* obj   = (const float*)d_in[2];
    const float* clsp  = (const float*)d_in[3];
    const int*   tgt   = (const int*)d_in[4];
    const int*   mins  = (const int*)d_in[5];
    float* part = (float*)d_ws;     // (2048) x 8 partials + magics, fully overwritten
    float* out  = (float*)d_out;

    yolo_fused<<<NPROD_ + 1, 256, 0, stream>>>(y_hat, ygt, obj, clsp, tgt, mins, part, out);
}

// Round 3
// 106.530 us; speedup vs baseline: 1.2049x; 1.2049x over previous
//
#include <hip/hip_runtime.h>
#include <math.h>
#include <stdint.h>

#define B_  16
#define NP_ 8192
#define NG_ 128
#define NC_ 80
#define PPB_ 64                // predictions per block (block = 256 thr, 4 quarters)
#define NBX_ (NP_ / PPB_)      // 128 blocks along preds per batch
#define NPROD_ (NBX_ * B_)     // 2048 producer blocks; block NPROD_ is the reducer
#define QCH_ (NC_ / 4)         // 20 logits per quarter in the CE phase

#define EPS_       1e-7f
#define IOU_THR_   0.5f
#define PEN_       0.1f
#define BOXW_      5.0f
#define SMALLSC_   2.0f
#define SMALLTH_   0.05f

// publication magics: a repeated single-dword poison fill can never match BOTH
#define MAG1_ 0xA5C3F00Du
#define MAG2_ 0x3E7B119Cu

// d_ws partials layout: part[blockIdx.x * 8 + i] for producer blocks.
// components: [n_match, n_valid, sum_loc, sum_ce, sum_pen, sum_bce, MAG1, MAG2]
//
// ALL cross-block traffic uses relaxed device-scope atomic RMW/loads (sc1,
// coherence-point ops, NO L2 writeback/invalidate -- the round-2 release/acquire
// protocol emitted buffer_wbl2/inv storms and tripled kernel time).
// Producer orders data-exch before magic-exch with a bare s_waitcnt vmcnt(0).
// Deadlock-free: only the reducer block waits; producers are independent.

__device__ __forceinline__ void pub_u32(uint32_t* p, uint32_t v) {
    __hip_atomic_exchange(p, v, __ATOMIC_RELAXED, __HIP_MEMORY_SCOPE_AGENT);
}
__device__ __forceinline__ uint32_t rd_u32(const uint32_t* p) {
    return __hip_atomic_load(p, __ATOMIC_RELAXED, __HIP_MEMORY_SCOPE_AGENT);
}

__global__ __launch_bounds__(256) void yolo_fused(
    const float* __restrict__ y_hat,   // (B, NP, 4) xywh
    const float* __restrict__ ygt,     // (B, NG, 4) xywh
    const float* __restrict__ obj,     // (B, NP)
    const float* __restrict__ clsp,    // (B, NP, NC)
    const int*   __restrict__ tgt,     // (B, NG)
    const int*   __restrict__ min_s,   // scalar (int)
    float*       part,                 // (NPROD_, 8) in d_ws
    float*       out)                  // scalar
{
    __shared__ float4 g4[NG_];                 // gt xyxy
    __shared__ float  garea[NG_], gws[NG_];
    __shared__ int    gtc[NG_];
    __shared__ float4 mbuf[4][PPB_];           // quarters publish {inter, uni, bi, 0}
    __shared__ float2 cpub[4][PPB_];           // per-quarter {local max, local expsum}
    __shared__ float  tlog[PPB_];              // target-class logit
    __shared__ float  bsum[16][6];             // reducer: per-batch sums

    // ---------------- reducer block: poll magics (relaxed), tree-reduce ------
    if (blockIdx.x == NPROD_) {
        const int t   = threadIdx.x;           // 0..255
        const int b   = t >> 4;                // batch 0..15
        const int sub = t & 15;                // 16 lanes per batch
        float v[6] = {0.f, 0.f, 0.f, 0.f, 0.f, 0.f};
        for (int k = 0; k < NBX_ / 16; ++k) {  // 8 slots per lane
            uint32_t* us = (uint32_t*)(part + ((size_t)b * NBX_ + sub + 16 * k) * 8);
            for (;;) {
                uint32_t m1 = rd_u32(&us[6]);
                uint32_t m2 = rd_u32(&us[7]);
                if (m1 == MAG1_ && m2 == MAG2_) break;
                __builtin_amdgcn_s_sleep(1);
            }
            // data words were exch'd (coherence point) BEFORE the magics: safe
            #pragma unroll
            for (int i = 0; i < 6; ++i) v[i] += __uint_as_float(rd_u32(&us[i]));
        }
        #pragma unroll
        for (int i = 0; i < 6; ++i) {          // reduce the 16-lane group
            v[i] += __shfl_xor(v[i], 1, 64);
            v[i] += __shfl_xor(v[i], 2, 64);
            v[i] += __shfl_xor(v[i], 4, 64);
            v[i] += __shfl_xor(v[i], 8, 64);
        }
        if (sub == 0) {
            #pragma unroll
            for (int i = 0; i < 6; ++i) bsum[b][i] = v[i];
        }
        __syncthreads();
        if (t < 16) {
            float nm = bsum[t][0], nv = bsum[t][1];
            float loc = nm > 0.f ? bsum[t][2] / nm : 0.f;
            float ce  = nm > 0.f ? bsum[t][3] / nm : 0.f;
            float ob  = nv > 0.f ? bsum[t][5] / nv : 0.f;
            float per = BOXW_ * loc + ob + bsum[t][4] + ce;
            float pbv = 0.f, cnt = 0.f;
            if (nv > 0.f) { pbv = per; cnt = 1.f; }
            pbv += __shfl_xor(pbv, 1, 64); cnt += __shfl_xor(cnt, 1, 64);
            pbv += __shfl_xor(pbv, 2, 64); cnt += __shfl_xor(cnt, 2, 64);
            pbv += __shfl_xor(pbv, 4, 64); cnt += __shfl_xor(cnt, 4, 64);
            pbv += __shfl_xor(pbv, 8, 64); cnt += __shfl_xor(cnt, 8, 64);
            if (t == 0) out[0] = pbv / fmaxf(cnt, 1.f);
        }
        return;
    }

    // ---------------- producer blocks ----------------------------------------
    const int b   = blockIdx.x / NBX_;
    const int tid = threadIdx.x;
    const int pl  = tid & 63;                  // local pred id (lane)
    const int q   = tid >> 6;                  // quarter: IoU j in [32q, 32q+32)
    const int p   = (blockIdx.x % NBX_) * PPB_ + pl;

    // stage GT boxes: xywh -> xyxy(float4), area, small-obj weight, class
    if (tid < NG_) {
        float4 gb = *(const float4*)(ygt + ((size_t)b * NG_ + tid) * 4);
        float x1 = gb.x - gb.z * 0.5f, y1 = gb.y - gb.w * 0.5f;
        float x2 = gb.x + gb.z * 0.5f, y2 = gb.y + gb.w * 0.5f;
        g4[tid] = make_float4(x1, y1, x2, y2);
        garea[tid] = (x2 - x1) * (y2 - y1);
        gws[tid]   = ((gb.z < SMALLTH_) || (gb.w < SMALLTH_)) ? SMALLSC_ : 1.0f;
        gtc[tid]   = tgt[b * NG_ + tid];
    }
    __syncthreads();

    const float min_score = (float)min_s[0];

    // pred box -> xyxy (all 4 quarters of a pred load the same box; L1-served)
    float4 pb = *(const float4*)(y_hat + ((size_t)b * NP_ + p) * 4);
    float px1 = pb.x - pb.z * 0.5f, py1 = pb.y - pb.w * 0.5f;
    float px2 = pb.x + pb.z * 0.5f, py2 = pb.y + pb.w * 0.5f;
    float area_p = (px2 - px1) * (py2 - py1);

    // quarter-range argmax IoU, division-free (unions > 0).
    // strict '>' + ascending j == first-index (jnp.argmax) semantics.
    float bi_inter = -1.0f, bi_union = 1.0f;
    const int j0 = q * 32;
    int bi = j0;
    #pragma unroll 8
    for (int jj = 0; jj < 32; ++jj) {
        int j = j0 + jj;
        float4 g = g4[j];                       // wave-uniform addr -> LDS broadcast
        float w = fmaxf(fminf(px2, g.z) - fmaxf(px1, g.x), 0.0f);
        float h = fmaxf(fminf(py2, g.w) - fmaxf(py1, g.y), 0.0f);
        float inter = w * h;
        float uni = area_p + garea[j] - inter;  // reference iou_mat has no eps
        bool better = inter * bi_union > bi_inter * uni;
        bi_inter = better ? inter : bi_inter;
        bi_union = better ? uni   : bi_union;
        bi       = better ? j     : bi;
    }

    mbuf[q][pl] = make_float4(bi_inter, bi_union, (float)bi, 0.f);
    __syncthreads();

    // ALL quarters merge in ascending quarter order (identical result per pred;
    // strict > keeps lowest j on ties == jnp.argmax)
    {
        float4 m0 = mbuf[0][pl];
        bi_inter = m0.x; bi_union = m0.y; bi = (int)m0.z;
        #pragma unroll
        for (int k = 1; k < 4; ++k) {
            float4 o = mbuf[k][pl];
            if (o.x * bi_union > bi_inter * o.y) {
                bi_inter = o.x; bi_union = o.y; bi = (int)o.z;
            }
        }
    }
    float max_iou = bi_inter / bi_union;

    float s = obj[(size_t)b * NP_ + p];         // same addr in all quarters; cached
    bool valid   = s > min_score;
    bool matched = valid && (max_iou > IOU_THR_);

    // ---- CE softmax, 4-way parallel, ONE barrier: each quarter publishes its
    // local (max, sum exp(x - local_max)); quarter 0 rescales and combines. ----
    const float* rowq = clsp + ((size_t)b * NP_ + p) * NC_ + q * QCH_;
    if (matched) {
        float4 v0 = ((const float4*)rowq)[0];
        float4 v1 = ((const float4*)rowq)[1];
        float4 v2 = ((const float4*)rowq)[2];
        float4 v3 = ((const float4*)rowq)[3];
        float4 v4 = ((const float4*)rowq)[4];
        float m = fmaxf(
            fmaxf(fmaxf(fmaxf(v0.x, v0.y), fmaxf(v0.z, v0.w)),
                  fmaxf(fmaxf(v1.x, v1.y), fmaxf(v1.z, v1.w))),
            fmaxf(fmaxf(fmaxf(v2.x, v2.y), fmaxf(v2.z, v2.w)),
                  fmaxf(fmaxf(fmaxf(v3.x, v3.y), fmaxf(v3.z, v3.w)),
                        fmaxf(fmaxf(v4.x, v4.y), fmaxf(v4.z, v4.w)))));
        float se = 0.f;
        se += expf(v0.x - m) + expf(v0.y - m) + expf(v0.z - m) + expf(v0.w - m);
        se += expf(v1.x - m) + expf(v1.y - m) + expf(v1.z - m) + expf(v1.w - m);
        se += expf(v2.x - m) + expf(v2.y - m) + expf(v2.z - m) + expf(v2.w - m);
        se += expf(v3.x - m) + expf(v3.y - m) + expf(v3.z - m) + expf(v3.w - m);
        se += expf(v4.x - m) + expf(v4.y - m) + expf(v4.z - m) + expf(v4.w - m);
        cpub[q][pl] = make_float2(m, se);
        int tcl = gtc[bi];
        if (tcl / QCH_ == q)                    // owner quarter: line is L1-hot
            tlog[pl] = rowq[tcl - q * QCH_];
    }
    __syncthreads();

    if (q != 0) return;   // all waves already passed the last barrier

    float f_loc = 0.f, f_ce = 0.f, f_pen = 0.f, f_bce = 0.f;
    float n_m = matched ? 1.f : 0.f;
    float n_v = valid   ? 1.f : 0.f;
    if (valid && !matched) f_pen = PEN_ * s;

    if (valid) {
        float lbl = matched ? 1.f : 0.f;
        float bce = fmaxf(s, 0.f) - s * lbl + log1pf(expf(-fabsf(s)));
        float w_obj = (matched && s < 0.5f) ? 2.f : 1.f;
        f_bce = bce * w_obj;
    }

    if (matched) {
        float wsm = gws[bi];
        float4 g = g4[bi];
        float bx1 = g.x, by1 = g.y, bx2 = g.z, by2 = g.w;
        // CIoU(pred, gt[bi]) op-for-op with reference (with eps)
        float b1a = (px2 - px1) * (py2 - py1);
        float b2a = (bx2 - bx1) * (by2 - by1);
        float iw = fmaxf(fminf(px2, bx2) - fmaxf(px1, bx1), 0.f);
        float ih = fmaxf(fminf(py2, by2) - fmaxf(py1, by1), 0.f);
        float inter = iw * ih;
        float uni = b1a + b2a - inter + EPS_;
        float iou = inter / uni;
        float cw = fmaxf(px2, bx2) - fminf(px1, bx1);
        float ch = fmaxf(py2, by2) - fminf(py1, by1);
        float c2 = cw * cw + ch * ch + EPS_;
        float dx = (px1 + px2) * 0.5f - (bx1 + bx2) * 0.5f;
        float dy = (py1 + py2) * 0.5f - (by1 + by2) * 0.5f;
        float rho2 = dx * dx + dy * dy;
        float w1 = px2 - px1, h1 = py2 - py1;
        float w2 = bx2 - bx1, h2 = by2 - by1;
        float dat = atanf(w1 / (h1 + EPS_)) - atanf(w2 / (h2 + EPS_));
        float v = (float)(4.0 / (M_PI * M_PI)) * dat * dat;
        float alpha = v / (1.f - iou + v + EPS_);
        float ciou = iou - (rho2 / c2 + alpha * v);
        f_loc = (1.f - ciou) * wsm;

        // combine the 4 quarter softmax partials (rescale to global max)
        float2 c0 = cpub[0][pl], c1 = cpub[1][pl], c2q = cpub[2][pl], c3 = cpub[3][pl];
        float M = fmaxf(fmaxf(c0.x, c1.x), fmaxf(c2q.x, c3.x));
        float se = c0.y  * expf(c0.x  - M) + c1.y * expf(c1.x - M)
                 + c2q.y * expf(c2q.x - M) + c3.y * expf(c3.x - M);
        float ce = -(tlog[pl] - M - logf(se));
        f_ce = ce * wsm;
    }

    // wave 0 owns the reduce: shuffle-reduce and publish the block's slot
    float vals[6] = { n_m, n_v, f_loc, f_ce, f_pen, f_bce };
    #pragma unroll
    for (int i = 0; i < 6; ++i) {
        float v = vals[i];
        #pragma unroll
        for (int off = 32; off > 0; off >>= 1)
            v += __shfl_down(v, off, 64);
        vals[i] = v;
    }
    if (pl == 0) {
        uint32_t* us = (uint32_t*)(part + (size_t)blockIdx.x * 8);
        #pragma unroll
        for (int i = 0; i < 6; ++i) pub_u32(&us[i], __float_as_uint(vals[i]));
        // order: data RMWs must COMPLETE (reach coherence point) before magics
        asm volatile("s_waitcnt vmcnt(0)" ::: "memory");
        pub_u32(&us[7], MAG2_);
        pub_u32(&us[6], MAG1_);
    }
}

extern "C" void kernel_launch(void* const* d_in, const int* in_sizes, int n_in,
                              void* d_out, int out_size, void* d_ws, size_t ws_size,
                              hipStream_t stream) {
    const float* y_hat = (const float*)d_in[0];
    const float* ygt   = (const float*)d_in[1];
    const float* obj   = (const float*)d_in[2];
    const float* clsp  = (const float*)d_in[3];
    const int*   tgt   = (const int*)d_in[4];
    const int*   mins  = (const int*)d_in[5];
    float* part = (float*)d_ws;     // (2048) x 8 partials + magics, fully overwritten
    float* out  = (float*)d_out;

    yolo_fused<<<NPROD_ + 1, 256, 0, stream>>>(y_hat, ygt, obj, clsp, tgt, mins, part, out);
}

// Round 4
// 102.751 us; speedup vs baseline: 1.2492x; 1.0368x over previous
//
#include <hip/hip_runtime.h>
#include <math.h>

#define B_  16
#define NP_ 8192
#define NG_ 128
#define NC_ 80
#define PPB_ 64                // predictions per block (block = 256 thr, 4 quarters)
#define NBX_ (NP_ / PPB_)      // 128 blocks along preds per batch
#define QCH_ (NC_ / 4)         // 20 logits per quarter in the CE phase

#define EPS_       1e-7f
#define IOU_THR_   0.5f
#define PEN_       0.1f
#define BOXW_      5.0f
#define SMALLSC_   2.0f
#define SMALLTH_   0.05f

// d_ws partials layout: part[(b*NBX_ + bx)*8 + i], every block writes its own
// slot unconditionally (two float4 stores) -> no zero-init, no atomics.
// components i: [n_match, n_valid, sum_loc, sum_ce] [sum_pen, sum_bce, 0, 0]

__global__ __launch_bounds__(256) void yolo_main(
    const float* __restrict__ y_hat,   // (B, NP, 4) xywh
    const float* __restrict__ ygt,     // (B, NG, 4) xywh
    const float* __restrict__ obj,     // (B, NP)
    const float* __restrict__ clsp,    // (B, NP, NC)
    const int*   __restrict__ tgt,     // (B, NG)
    const int*   __restrict__ min_s,   // scalar (int)
    float* __restrict__ part)          // (B*NBX_, 8)
{
    __shared__ float4 g4[NG_];                 // gt xyxy
    __shared__ float  garea[NG_], gws[NG_];
    __shared__ int    gtc[NG_];
    __shared__ float4 mbuf[4][PPB_];           // all quarters publish {inter, uni, bi, 0}
    __shared__ float  cmax[4][PPB_];           // per-quarter max of its 20 logits
    __shared__ float  csum[4][PPB_];           // per-quarter sum of exp(x - M)
    __shared__ float  tlog[PPB_];              // target-class logit

    const int b   = blockIdx.y;
    const int tid = threadIdx.x;
    const int pl  = tid & 63;                  // local pred id (lane)
    const int q   = tid >> 6;                  // quarter: IoU j in [32q, 32q+32)
    const int p   = blockIdx.x * PPB_ + pl;

    // hoisted global loads: issue BEFORE the staging barrier so HBM latency
    // hides under GT staging (values independent of LDS contents)
    float4 pb = *(const float4*)(y_hat + ((size_t)b * NP_ + p) * 4);
    float s   = obj[(size_t)b * NP_ + p];      // same addr in all quarters; cached
    const float min_score = (float)min_s[0];

    // stage GT boxes: xywh -> xyxy(float4), area, small-obj weight, class
    if (tid < NG_) {
        float4 gb = *(const float4*)(ygt + ((size_t)b * NG_ + tid) * 4);
        float x1 = gb.x - gb.z * 0.5f, y1 = gb.y - gb.w * 0.5f;
        float x2 = gb.x + gb.z * 0.5f, y2 = gb.y + gb.w * 0.5f;
        g4[tid] = make_float4(x1, y1, x2, y2);
        garea[tid] = (x2 - x1) * (y2 - y1);
        gws[tid]   = ((gb.z < SMALLTH_) || (gb.w < SMALLTH_)) ? SMALLSC_ : 1.0f;
        gtc[tid]   = tgt[b * NG_ + tid];
    }
    __syncthreads();

    float px1 = pb.x - pb.z * 0.5f, py1 = pb.y - pb.w * 0.5f;
    float px2 = pb.x + pb.z * 0.5f, py2 = pb.y + pb.w * 0.5f;
    float area_p = (px2 - px1) * (py2 - py1);

    // quarter-range argmax IoU, division-free (unions > 0).
    // strict '>' + ascending j == first-index (jnp.argmax) semantics.
    float bi_inter = -1.0f, bi_union = 1.0f;
    const int j0 = q * 32;
    int bi = j0;
    #pragma unroll 8
    for (int jj = 0; jj < 32; ++jj) {
        int j = j0 + jj;
        float4 g = g4[j];                       // wave-uniform addr -> LDS broadcast
        float w = fmaxf(fminf(px2, g.z) - fmaxf(px1, g.x), 0.0f);
        float h = fmaxf(fminf(py2, g.w) - fmaxf(py1, g.y), 0.0f);
        float inter = w * h;
        float uni = area_p + garea[j] - inter;  // reference iou_mat has no eps
        bool better = inter * bi_union > bi_inter * uni;
        bi_inter = better ? inter : bi_inter;
        bi_union = better ? uni   : bi_union;
        bi       = better ? j     : bi;
    }

    mbuf[q][pl] = make_float4(bi_inter, bi_union, (float)bi, 0.f);
    __syncthreads();

    // ALL quarters merge in ascending quarter order (identical result per pred;
    // strict > keeps lowest j on ties == jnp.argmax)
    {
        float4 m0 = mbuf[0][pl];
        bi_inter = m0.x; bi_union = m0.y; bi = (int)m0.z;
        #pragma unroll
        for (int k = 1; k < 4; ++k) {
            float4 o = mbuf[k][pl];
            if (o.x * bi_union > bi_inter * o.y) {
                bi_inter = o.x; bi_union = o.y; bi = (int)o.z;
            }
        }
    }
    float max_iou = bi_inter / bi_union;

    bool valid   = s > min_score;
    bool matched = valid && (max_iou > IOU_THR_);

    // ---- CE softmax, 4-way parallel: quarter q owns logit cols [20q, 20q+20) ----
    const float* rowq = clsp + ((size_t)b * NP_ + p) * NC_ + q * QCH_;
    float4 v0, v1, v2, v3, v4;
    if (matched) {
        v0 = ((const float4*)rowq)[0];
        v1 = ((const float4*)rowq)[1];
        v2 = ((const float4*)rowq)[2];
        v3 = ((const float4*)rowq)[3];
        v4 = ((const float4*)rowq)[4];
        float m = fmaxf(
            fmaxf(fmaxf(fmaxf(v0.x, v0.y), fmaxf(v0.z, v0.w)),
                  fmaxf(fmaxf(v1.x, v1.y), fmaxf(v1.z, v1.w))),
            fmaxf(fmaxf(fmaxf(v2.x, v2.y), fmaxf(v2.z, v2.w)),
                  fmaxf(fmaxf(fmaxf(v3.x, v3.y), fmaxf(v3.z, v3.w)),
                        fmaxf(fmaxf(v4.x, v4.y), fmaxf(v4.z, v4.w)))));
        cmax[q][pl] = m;
    }
    __syncthreads();

    float Mall = 0.f;
    if (matched) {
        // global max: order-independent (fmax associative on finite data) -> bit-exact
        Mall = fmaxf(fmaxf(cmax[0][pl], cmax[1][pl]), fmaxf(cmax[2][pl], cmax[3][pl]));
        float se = 0.f;
        se += expf(v0.x - Mall) + expf(v0.y - Mall) + expf(v0.z - Mall) + expf(v0.w - Mall);
        se += expf(v1.x - Mall) + expf(v1.y - Mall) + expf(v1.z - Mall) + expf(v1.w - Mall);
        se += expf(v2.x - Mall) + expf(v2.y - Mall) + expf(v2.z - Mall) + expf(v2.w - Mall);
        se += expf(v3.x - Mall) + expf(v3.y - Mall) + expf(v3.z - Mall) + expf(v3.w - Mall);
        se += expf(v4.x - Mall) + expf(v4.y - Mall) + expf(v4.z - Mall) + expf(v4.w - Mall);
        csum[q][pl] = se;
        int t = gtc[bi];
        if (t / QCH_ == q)                      // owner quarter: line is L1-hot
            tlog[pl] = rowq[t - q * QCH_];
    }
    __syncthreads();

    if (q != 0) return;   // all waves already passed the last barrier

    float f_loc = 0.f, f_ce = 0.f, f_pen = 0.f, f_bce = 0.f;
    float n_m = matched ? 1.f : 0.f;
    float n_v = valid   ? 1.f : 0.f;
    if (valid && !matched) f_pen = PEN_ * s;

    if (valid) {
        float lbl = matched ? 1.f : 0.f;
        float bce = fmaxf(s, 0.f) - s * lbl + log1pf(expf(-fabsf(s)));
        float w_obj = (matched && s < 0.5f) ? 2.f : 1.f;
        f_bce = bce * w_obj;
    }

    if (matched) {
        float wsm = gws[bi];
        float4 g = g4[bi];
        float bx1 = g.x, by1 = g.y, bx2 = g.z, by2 = g.w;
        // CIoU(pred, gt[bi]) op-for-op with reference (with eps)
        float b1a = (px2 - px1) * (py2 - py1);
        float b2a = (bx2 - bx1) * (by2 - by1);
        float iw = fmaxf(fminf(px2, bx2) - fmaxf(px1, bx1), 0.f);
        float ih = fmaxf(fminf(py2, by2) - fmaxf(py1, by1), 0.f);
        float inter = iw * ih;
        float uni = b1a + b2a - inter + EPS_;
        float iou = inter / uni;
        float cw = fmaxf(px2, bx2) - fminf(px1, bx1);
        float ch = fmaxf(py2, by2) - fminf(py1, by1);
        float c2 = cw * cw + ch * ch + EPS_;
        float dx = (px1 + px2) * 0.5f - (bx1 + bx2) * 0.5f;
        float dy = (py1 + py2) * 0.5f - (by1 + by2) * 0.5f;
        float rho2 = dx * dx + dy * dy;
        float w1 = px2 - px1, h1 = py2 - py1;
        float w2 = bx2 - bx1, h2 = by2 - by1;
        float dat = atanf(w1 / (h1 + EPS_)) - atanf(w2 / (h2 + EPS_));
        float v = (float)(4.0 / (M_PI * M_PI)) * dat * dat;
        float alpha = v / (1.f - iou + v + EPS_);
        float ciou = iou - (rho2 / c2 + alpha * v);
        f_loc = (1.f - ciou) * wsm;

        // combine the 4 quarter softmax partials
        float se = ((csum[0][pl] + csum[1][pl]) + csum[2][pl]) + csum[3][pl];
        float ce = -(tlog[pl] - Mall - logf(se));
        f_ce = ce * wsm;
    }

    // wave 0 owns the reduce: shuffle-reduce and write the block's slot (float4 x2)
    float vals[6] = { n_m, n_v, f_loc, f_ce, f_pen, f_bce };
    #pragma unroll
    for (int i = 0; i < 6; ++i) {
        float v = vals[i];
        #pragma unroll
        for (int off = 32; off > 0; off >>= 1)
            v += __shfl_down(v, off, 64);
        vals[i] = v;
    }
    if (pl == 0) {
        float4* slot = (float4*)(part + ((size_t)b * NBX_ + blockIdx.x) * 8);
        slot[0] = make_float4(vals[0], vals[1], vals[2], vals[3]);
        slot[1] = make_float4(vals[4], vals[5], 0.f, 0.f);
    }
}

// 256 threads: 16 lanes per batch, each lane sums 8 of the 128 block-slots
// (same summation grouping as the round-3 reducer, verified absmax = 0.0)
__global__ __launch_bounds__(256) void yolo_final(const float* __restrict__ part,
                                                  float* __restrict__ out)
{
    __shared__ float bsum[16][6];
    const int t   = threadIdx.x;   // 0..255
    const int b   = t >> 4;        // batch 0..15
    const int sub = t & 15;        // 16 lanes per batch

    float v[6] = {0.f, 0.f, 0.f, 0.f, 0.f, 0.f};
    #pragma unroll
    for (int k = 0; k < NBX_ / 16; ++k) {      // 8 slots per lane, independent
        const float4* slot = (const float4*)(part + ((size_t)b * NBX_ + sub + 16 * k) * 8);
        float4 a = slot[0];
        float4 c = slot[1];
        v[0] += a.x; v[1] += a.y; v[2] += a.z; v[3] += a.w;
        v[4] += c.x; v[5] += c.y;
    }
    #pragma unroll
    for (int i = 0; i < 6; ++i) {              // reduce the 16-lane group
        v[i] += __shfl_xor(v[i], 1, 64);
        v[i] += __shfl_xor(v[i], 2, 64);
        v[i] += __shfl_xor(v[i], 4, 64);
        v[i] += __shfl_xor(v[i], 8, 64);
    }
    if (sub == 0) {
        #pragma unroll
        for (int i = 0; i < 6; ++i) bsum[b][i] = v[i];
    }
    __syncthreads();
    if (t < 16) {
        float nm = bsum[t][0], nv = bsum[t][1];
        float loc = nm > 0.f ? bsum[t][2] / nm : 0.f;
        float ce  = nm > 0.f ? bsum[t][3] / nm : 0.f;
        float ob  = nv > 0.f ? bsum[t][5] / nv : 0.f;
        float per = BOXW_ * loc + ob + bsum[t][4] + ce;
        float pbv = 0.f, cnt = 0.f;
        if (nv > 0.f) { pbv = per; cnt = 1.f; }
        pbv += __shfl_xor(pbv, 1, 64); cnt += __shfl_xor(cnt, 1, 64);
        pbv += __shfl_xor(pbv, 2, 64); cnt += __shfl_xor(cnt, 2, 64);
        pbv += __shfl_xor(pbv, 4, 64); cnt += __shfl_xor(cnt, 4, 64);
        pbv += __shfl_xor(pbv, 8, 64); cnt += __shfl_xor(cnt, 8, 64);
        if (t == 0) out[0] = pbv / fmaxf(cnt, 1.f);
    }
}

extern "C" void kernel_launch(void* const* d_in, const int* in_sizes, int n_in,
                              void* d_out, int out_size, void* d_ws, size_t ws_size,
                              hipStream_t stream) {
    const float* y_hat = (const float*)d_in[0];
    const float* ygt   = (const float*)d_in[1];
    const float* obj   = (const float*)d_in[2];
    const float* clsp  = (const float*)d_in[3];
    const int*   tgt   = (const int*)d_in[4];
    const int*   mins  = (const int*)d_in[5];
    float* part = (float*)d_ws;     // (16*128) x 8 partials, fully overwritten
    float* out  = (float*)d_out;

    dim3 grid(NBX_, B_);
    yolo_main<<<grid, 256, 0, stream>>>(y_hat, ygt, obj, clsp, tgt, mins, part);
    yolo_final<<<1, 256, 0, stream>>>(part, out);
}